// Round 6
// baseline (1208.547 us; speedup 1.0000x reference)
//
#include <hip/hip_runtime.h>
#include <cstdint>
#include <cstddef>

// B=2, H=16, S=2048, D=64. fp32 inputs (Q,K,V), mask (int32/uint8 auto-detected),
// fp32 outputs: [context | attn_prob] concatenated.
//
// v4c (v4 resubmit #2 after back-to-back infra timeouts; unchanged):
//  - phase 4 DELETED: prob is written inside the PV loop from the A-frags
//    (each wave owns a quarter of the k-range, g==wave). Writes overlap MFMA
//    for the whole kernel instead of a serial tail pass.
//  - phase 2 rowsum via 256B LDS buffer (was 2 global round-trips + 2 barriers;
//    now 1 barrier, no redg/invg).
//  - nontemporal stores for prob/ctx (write-once; stop evicting K/Vt from L2),
//    nontemporal loads in packmask (134MB read-once).
//  - v_cvt_pk_bf16_f32 for P pack (1 instr / 2 vals, RNE = same as f2bf);
//    native exp2 with folded 0.125*log2(e) constant.
#define S_LEN 2048
#define D_HEAD 64
#define NBH 32

typedef __attribute__((ext_vector_type(8))) short short8;
typedef __attribute__((ext_vector_type(8))) unsigned short ushort8;
typedef __attribute__((ext_vector_type(2))) unsigned int ui2;
typedef __attribute__((ext_vector_type(4))) unsigned int ui4;
typedef __attribute__((ext_vector_type(4))) float floatx4;

__device__ __forceinline__ unsigned short f2bf(float f){
  union { float f; unsigned int i; } v; v.f = f;
  unsigned int u = v.i;
  u += 0x7fffu + ((u >> 16) & 1u);     // RNE
  return (unsigned short)(u >> 16);
}
__device__ __forceinline__ float bf2f(unsigned short u){
  union { unsigned int i; float f; } v; v.i = ((unsigned int)u) << 16; return v.f;
}
// HW pack: lo -> bits[15:0], hi -> bits[31:16], RNE (matches f2bf exactly)
__device__ __forceinline__ unsigned int cvtpk(float lo, float hi){
  unsigned int r;
  asm("v_cvt_pk_bf16_f32 %0, %1, %2" : "=v"(r) : "v"(lo), "v"(hi));
  return r;
}

// XOR swizzle at 16B granularity, 4-bit (16-slot) spread. P tile stays 64KB.
__device__ __forceinline__ int swz(int row, int col){
  return row * S_LEN + ((((col >> 3) ^ row) & 15) << 3)
                     + (((col >> 3) & ~15) << 3) + (col & 7);
}

// ---- mask width detect: int32 0/1 -> every 4B word <= 1; uint8 0/1 -> words >1 whp.
__global__ void detect_mask_kernel(const unsigned int* __restrict__ m, int* __restrict__ flag){
  __shared__ int f;
  if (threadIdx.x == 0) f = 0;
  __syncthreads();
  if (m[threadIdx.x] > 1u) atomicOr(&f, 1);
  __syncthreads();
  if (threadIdx.x == 0) *flag = f;   // 0 = int32, 1 = uint8
}

// ---- mask -> 1 bit/element. Word w holds cols [32w, 32w+32) of the flattened
// [BH*S, S] mask; bit j = col 32w+j. One thread = one output word.
__global__ void packmask_kernel(const void* __restrict__ maskp, const int* __restrict__ flag,
                                unsigned int* __restrict__ pm){
  const int w = blockIdx.x * 256 + threadIdx.x;
  unsigned int bits = 0;
  if (*flag){   // uint8
    const ui4* mb = (const ui4*)((const unsigned char*)maskp + (size_t)w * 32);
    const ui4 x0 = __builtin_nontemporal_load(mb);
    const ui4 x1 = __builtin_nontemporal_load(mb + 1);
#pragma unroll
    for (int i = 0; i < 4; ++i){
      const unsigned int a = x0[i], b = x1[i];
#pragma unroll
      for (int j = 0; j < 4; ++j){
        bits |= (((a >> (8 * j)) & 0xffu) ? 1u : 0u) << (4 * i + j);
        bits |= (((b >> (8 * j)) & 0xffu) ? 1u : 0u) << (16 + 4 * i + j);
      }
    }
  } else {      // int32
    const ui4* mi = (const ui4*)((const unsigned int*)maskp + (size_t)w * 32);
#pragma unroll
    for (int i = 0; i < 8; ++i){
      const ui4 x = __builtin_nontemporal_load(mi + i);
#pragma unroll
      for (int j = 0; j < 4; ++j)
        bits |= (x[j] ? 1u : 0u) << (i * 4 + j);
    }
  }
  pm[w] = bits;
}

// ---- K fp32 -> Kb bf16 (same layout). 8 elems/thread.
__global__ void convK_kernel(const float* __restrict__ K, unsigned short* __restrict__ Kb){
  const size_t i = ((size_t)blockIdx.x * 256 + threadIdx.x) * 8;
  floatx4 x0 = *(const floatx4*)(K + i);
  floatx4 x1 = *(const floatx4*)(K + i + 4);
  ushort8 o;
#pragma unroll
  for (int j = 0; j < 4; ++j){ o[j] = f2bf(x0[j]); o[4 + j] = f2bf(x1[j]); }
  *(ushort8*)(Kb + i) = o;
}

// ---- V fp32 -> Vt bf16 transposed: Vt[bh][n][k] (k contiguous for PV B-frags).
__global__ void vtrans_kernel(const float* __restrict__ V, unsigned short* __restrict__ Vt){
  const int bh = blockIdx.y;
  const int n  = threadIdx.x & 63;
  const int k0 = blockIdx.x * 32 + (threadIdx.x >> 6) * 8;
  const float* Vp = V + (size_t)bh * S_LEN * D_HEAD;
  ushort8 o;
#pragma unroll
  for (int i = 0; i < 8; ++i) o[i] = f2bf(Vp[(size_t)(k0 + i) * D_HEAD + n]);
  *(ushort8*)(Vt + (size_t)bh * D_HEAD * S_LEN + (size_t)n * S_LEN + k0) = o;
}

// ---- fused attention: per block = 16 q-rows x full S.
// SWAPPED QK^T: c = mfma(K_frag, Q_frag) -> C col=lane&15 = q-row,
// row=quad*4+reg = score-col (verified r1-r3). Lane (r16,quad) owns q-row r16,
// score-cols {16t + quad*4 + i}.
__global__ __launch_bounds__(256, 2) void attn_kernel(
    const float* __restrict__ Q, const unsigned short* __restrict__ Kb,
    const unsigned int* __restrict__ pm,
    const unsigned short* __restrict__ Vt,
    float* __restrict__ prob, float* __restrict__ ctx){

  __shared__ unsigned short Pt[16 * S_LEN];   // exactly 64 KB
  __shared__ float redL[64];                  // per-wave rowsum partials

  // XCD-aware remap: 4096 blocks = 8 XCD x (4 heads x 128 qt).
  const int lin  = blockIdx.y * gridDim.x + blockIdx.x;
  const int xcd  = lin & 7;
  const int sub  = lin >> 3;
  const int bh   = xcd * 4 + (sub & 3);
  const int qt   = sub >> 2;

  const int q0g  = bh * S_LEN + qt * 16;      // row index into flattened [BH*S]
  const int tid  = threadIdx.x;
  const int wave = tid >> 6;
  const int lane = tid & 63;
  const int quad = lane >> 4;
  const int r16  = lane & 15;

  // ---- Phase 1: QK^T + mask + exp -> Pt (bf16, swizzled) + rowsum partials ----
  const float* qrow = Q + (size_t)(q0g + r16) * D_HEAD + quad * 8;
  short8 a0, a1;
  {
    floatx4 x0 = *(const floatx4*)(qrow);
    floatx4 x1 = *(const floatx4*)(qrow + 4);
    floatx4 y0 = *(const floatx4*)(qrow + 32);
    floatx4 y1 = *(const floatx4*)(qrow + 36);
#pragma unroll
    for (int j = 0; j < 4; ++j){
      a0[j] = (short)f2bf(x0[j]); a0[4 + j] = (short)f2bf(x1[j]);
      a1[j] = (short)f2bf(y0[j]); a1[4 + j] = (short)f2bf(y1[j]);
    }
  }

  // packed mask: row (q0g+r16) has 64 words; this wave's strip = words [wave*16, +16)
  const unsigned int* mrow = pm + (size_t)(q0g + r16) * 64 + wave * 16;
  const unsigned short* kbase = Kb + (size_t)bh * S_LEN * D_HEAD;

  float racc = 0.f;
  ui4 mcur = *(const ui4*)(mrow);
  for (int tt = 0; tt < 4; ++tt){
    const ui4 mnext = (tt < 3) ? *(const ui4*)(mrow + (tt + 1) * 4) : mcur;
#pragma unroll
    for (int tj = 0; tj < 8; ++tj){
      const int t  = tt * 8 + tj;
      const int s0 = wave * 512 + t * 16;
      const unsigned short* krow = kbase + (size_t)(s0 + r16) * D_HEAD + quad * 8;
      const short8 b0 = *(const short8*)(krow);
      const short8 b1 = *(const short8*)(krow + 32);
      floatx4 c = {0.f, 0.f, 0.f, 0.f};
      c = __builtin_amdgcn_mfma_f32_16x16x32_bf16(b0, a0, c, 0, 0, 0);  // swapped
      c = __builtin_amdgcn_mfma_f32_16x16x32_bf16(b1, a1, c, 0, 0, 0);
      const unsigned int bits = mcur[tj >> 1] >> (16 * (tj & 1) + 4 * quad);
      float p[4];
#pragma unroll
      for (int i = 0; i < 4; ++i){
        // exp(x/8) = exp2(x * 0.125*log2(e)); masked -> exactly 0 (ref underflows too)
        p[i] = ((bits >> i) & 1u) ? 0.0f
             : __builtin_amdgcn_exp2f(c[i] * 0.18033688011f);
        racc += p[i];
      }
      const ui2 w = { cvtpk(p[0], p[1]), cvtpk(p[2], p[3]) };
      *(ui2*)(&Pt[swz(r16, s0 + quad * 4)]) = w;   // 8B aligned within a 16B group
    }
    mcur = mnext;
  }

  // ---- Phase 2: rowsums via LDS (one barrier, no global round-trip) ----
  racc += __shfl_xor(racc, 16);
  racc += __shfl_xor(racc, 32);          // all lanes: full partial for row r16, this wave
  if (lane < 16) redL[wave * 16 + lane] = racc;
  __syncthreads();                       // also orders all Pt writes
  const float s = redL[r16] + redL[16 + r16] + redL[32 + r16] + redL[48 + r16];
  const float inv_r = (s > 0.f) ? (1.0f / s) : 0.0f;   // inv for row r16

  // ---- Phase 3: PV (wave w -> ctx cols [16w,16w+16)) + fused prob writes ----
  // A-frag aa = P[r16][kk*32 + quad*8 .. +8] -- exactly 8 consecutive prob
  // elements of row r16. Wave g==wave writes k-range [g*512, g*512+512):
  // each col chunk written exactly once, 128B-contiguous per row.
  const unsigned short* vrow = Vt + (size_t)bh * D_HEAD * S_LEN
                                  + (size_t)(wave * 16 + r16) * S_LEN + quad * 8;
  float* prow = prob + (size_t)(q0g + r16) * S_LEN;
  floatx4 cA = {0.f,0.f,0.f,0.f}, cB = {0.f,0.f,0.f,0.f};

  for (int g = 0; g < 4; ++g){
    const bool wr = (g == wave);         // wave-uniform
#pragma unroll 4
    for (int k2 = 0; k2 < 16; k2 += 2){
      const int kk = g * 16 + k2;
      const short8 bv0 = *(const short8*)(vrow + kk * 32);
      const short8 aa0 = *(const short8*)(&Pt[swz(r16, kk * 32 + quad * 8)]);
      const short8 bv1 = *(const short8*)(vrow + (kk + 1) * 32);
      const short8 aa1 = *(const short8*)(&Pt[swz(r16, (kk + 1) * 32 + quad * 8)]);
      cA = __builtin_amdgcn_mfma_f32_16x16x32_bf16(aa0, bv0, cA, 0, 0, 0);
      cB = __builtin_amdgcn_mfma_f32_16x16x32_bf16(aa1, bv1, cB, 0, 0, 0);
      if (wr){
        floatx4 o0, o1, o2, o3;
#pragma unroll
        for (int e = 0; e < 4; ++e){
          o0[e] = bf2f((unsigned short)aa0[e])     * inv_r;
          o1[e] = bf2f((unsigned short)aa0[4 + e]) * inv_r;
          o2[e] = bf2f((unsigned short)aa1[e])     * inv_r;
          o3[e] = bf2f((unsigned short)aa1[4 + e]) * inv_r;
        }
        float* pg = prow + kk * 32 + quad * 8;
        __builtin_nontemporal_store(o0, (floatx4*)(pg));
        __builtin_nontemporal_store(o1, (floatx4*)(pg + 4));
        __builtin_nontemporal_store(o2, (floatx4*)(pg + 32));
        __builtin_nontemporal_store(o3, (floatx4*)(pg + 36));
      }
    }
  }

  // ---- ctx store (overwrites the pm words this block consumed in phase 1) ----
  float inv4[4];
#pragma unroll
  for (int i = 0; i < 4; ++i) inv4[i] = __shfl(inv_r, quad * 4 + i, 64);
#pragma unroll
  for (int i = 0; i < 4; ++i){
    const float v = (cA[i] + cB[i]) * inv4[i];
    __builtin_nontemporal_store(v,
        ctx + (size_t)(q0g + quad * 4 + i) * D_HEAD + wave * 16 + r16);
  }
}

extern "C" void kernel_launch(void* const* d_in, const int* in_sizes, int n_in,
                              void* d_out, int out_size, void* d_ws, size_t ws_size,
                              hipStream_t stream) {
  const float* Q = (const float*)d_in[0];
  const float* K = (const float*)d_in[1];
  const float* V = (const float*)d_in[2];
  const void*  M = d_in[3];

  float* ctx  = (float*)d_out;
  float* prob = (float*)d_out + (size_t)NBH * S_LEN * D_HEAD;

  // packed mask lives in the ctx output region: 32*2048 rows x 64 words x 4B
  // = 16.78MB = exactly sizeof(ctx); identical 256B row stride. Each attn block
  // reads only the pm words (its 16 rows) it later overwrites with ctx.
  unsigned int* pm = (unsigned int*)d_out;

  // ws: [0,4) flag | [2MB,10MB) Kb | [10MB,18MB) Vt
  int*   flag = (int*)d_ws;
  unsigned short* Kb = (unsigned short*)((char*)d_ws + (2u << 20));
  unsigned short* Vt = (unsigned short*)((char*)d_ws + (10u << 20));

  hipLaunchKernelGGL(detect_mask_kernel, dim3(1), dim3(256), 0, stream,
                     (const unsigned int*)M, flag);
  hipLaunchKernelGGL(packmask_kernel, dim3((NBH * S_LEN * S_LEN / 32) / 256), dim3(256),
                     0, stream, M, flag, pm);
  hipLaunchKernelGGL(convK_kernel, dim3(2048), dim3(256), 0, stream, K, Kb);
  hipLaunchKernelGGL(vtrans_kernel, dim3(S_LEN/32, NBH), dim3(256), 0, stream, V, Vt);
  hipLaunchKernelGGL(attn_kernel, dim3(S_LEN/16, NBH), dim3(256), 0, stream,
                     Q, Kb, pm, Vt, prob, ctx);
}